// Round 7
// baseline (295.796 us; speedup 1.0000x reference)
//
#include <hip/hip_runtime.h>
#include <hip/hip_bf16.h>

// SubnetGate = gathered grouped GEMM (B=16384, K=512, N=512, E=8, col 0).
// R9: consolidation. Evidence: R0 (slowest gemm, 48us) still holds the best
// TOTAL (122.5) -- prep/launch overhead ate every gemm gain since. Fixes:
//  - prep = 8-block scatter ONLY (~4us). xg killed (net -48MB+launch vs
//    -16MB in gemm); Wtile phase killed (gemm stages W f32->bf16 itself,
//    same proven swizzled granule layout, address math verbatim).
//  - gemm grid EXACTLY 256 (8e x 4ns x 8 slots) = 1 block/CU uniform.
//    R8's 288 @ 1/CU made ~32 CUs serialize two full blocks. Slot-strided
//    m-loop (mc = slot, slot+8, ...) reuses the staged W across passes and
//    absorbs any count skew.
//  - W-stationary K=512 loop: barrier-free (R8-proven KLOOP/COMPUTE_Q),
//    f32-A register gather + pack (R0/R1-proven pattern). NO manual vmcnt
//    anywhere: one __syncthreads after LDS staging, compiler-managed waits.
//
// ws layout:
//   [0,      32)       int counts[8]
//   [4096,   528384)   int rowlist[8][16384]

#define NROWS   16384
#define KDIM    512
#define NDIM    512
#define NEXP    8
#define BM      256
#define BN      128
#define NT_PER  4
#define KT_PER  8
#define SLOTS   8
#define TILE_ELEMS (BN * 64)          // 8192 shorts = 16KB per kt-tile
#define WS_ROWLIST_OFF 4096

typedef __bf16        bf16x8 __attribute__((ext_vector_type(8)));
typedef float         f32x4  __attribute__((ext_vector_type(4)));
typedef unsigned int  u32x4  __attribute__((ext_vector_type(4)));

__device__ __forceinline__ unsigned int f2bf_u(float f) {
    unsigned int u = __builtin_bit_cast(unsigned int, f);
    return (u + 0x7FFFu + ((u >> 16) & 1u)) >> 16;   // RNE f32->bf16
}

__device__ __forceinline__ bf16x8 pack_bf8(f32x4 lo, f32x4 hi) {
    u32x4 w;
    w.x = f2bf_u(lo.x) | (f2bf_u(lo.y) << 16);
    w.y = f2bf_u(lo.z) | (f2bf_u(lo.w) << 16);
    w.z = f2bf_u(hi.x) | (f2bf_u(hi.y) << 16);
    w.w = f2bf_u(hi.z) | (f2bf_u(hi.w) << 16);
    return __builtin_bit_cast(bf16x8, w);
}

// ---------------- prep: scatter only (verbatim R6-proven) ----------------
// 8 blocks x 256 thr; block e scans all 16384 ids, 8 iters x (256 thr x 8
// rows), ballot+prefix compaction, zero atomics; counts[e] plain store.
__global__ void prep_kernel(const int* __restrict__ groups,
                            int* __restrict__ counts,
                            int* __restrict__ rowlist) {
    __shared__ int wcnt_s[4];
    __shared__ int woff_s[4];
    __shared__ int runb;
    const int tid = threadIdx.x;
    const int e   = blockIdx.x;
    const int w   = tid >> 6;
    const int ln  = tid & 63;
    const unsigned long long below = (ln == 63) ? ~0ull >> 1
                                                : (1ull << ln) - 1;
    int* dst = rowlist + e * NROWS;
    if (tid == 0) runb = 0;
    __syncthreads();
    for (int it = 0; it < NROWS / 2048; ++it) {      // 8 iterations
        int rbase = it * 2048 + tid * 8;
        u32x4 g0 = *(const u32x4*)&groups[rbase * 2];
        u32x4 g1 = *(const u32x4*)&groups[rbase * 2 + 4];
        u32x4 g2 = *(const u32x4*)&groups[rbase * 2 + 8];
        u32x4 g3 = *(const u32x4*)&groups[rbase * 2 + 12];
        bool h[8] = {(int)g0.x == e, (int)g0.z == e,
                     (int)g1.x == e, (int)g1.z == e,
                     (int)g2.x == e, (int)g2.z == e,
                     (int)g3.x == e, (int)g3.z == e};
        unsigned long long m[8];
        int c[8], tot = 0;
        #pragma unroll
        for (int jj = 0; jj < 8; ++jj) {
            m[jj] = __ballot(h[jj]);
            c[jj] = __popcll(m[jj]);
            tot += c[jj];
        }
        if (ln == 0) wcnt_s[w] = tot;
        __syncthreads();
        if (tid == 0) {
            int s = runb;
            #pragma unroll
            for (int i = 0; i < 4; ++i) { woff_s[i] = s; s += wcnt_s[i]; }
            runb = s;
        }
        __syncthreads();
        int base = woff_s[w];
        #pragma unroll
        for (int jj = 0; jj < 8; ++jj) {
            if (h[jj]) dst[base + __popcll(m[jj] & below)] = rbase + jj;
            base += c[jj];
        }
        __syncthreads();
    }
    if (tid == 0) counts[e] = runb;
}

// ---------------- gemm: W-stationary, self-staging ----------------
// Block = (e = bid&7 -> XCD pin; ns = (bid>>3)&3; slot = bid>>5). Grid 256.
// 512 thr = 8 waves; wave w owns rows [mc*256 + w*32, +32) x 128 cols.
// Prologue: stage W-slice (e,ns) f32 -> bf16 -> 128KB LDS, swizzled granule
//   layout (n,g) -> kt*16KB + n*128B + ((g)^(n&7))*16B  [prep-proven math];
//   ONE __syncthreads. Then for mc = slot, slot+8, ... while mc*256 < cnt:
//   barrier-free K=512 pass (A f32 reg-gather + pack, 1 K-quarter ahead).

extern __shared__ __align__(16) unsigned short Bsm[];   // 8 * 16KB = 128KB

#define LOAD_A_F32(QT, AR)                                                   \
    {                                                                        \
        _Pragma("unroll")                                                    \
        for (int _kh = 0; _kh < 4; ++_kh) {                                  \
            int _k0 = (QT) * 128 + _kh * 32 + q * 8;                         \
            const float* _p0 = afrow0 + _k0;                                 \
            const float* _p1 = afrow1 + _k0;                                 \
            AR[0][_kh] = pack_bf8(*(const f32x4*)_p0, *(const f32x4*)(_p0 + 4)); \
            AR[1][_kh] = pack_bf8(*(const f32x4*)_p1, *(const f32x4*)(_p1 + 4)); \
        }                                                                    \
    }

#define COMPUTE_Q(QT, AR)                                                    \
    {                                                                        \
        _Pragma("unroll")                                                    \
        for (int _kh = 0; _kh < 4; ++_kh) {                                  \
            const int _t  = (QT) * 4 + _kh;                                  \
            const int _kt = _t >> 1;                                         \
            const int _g  = (_t & 1) * 4 + q;                                \
            _Pragma("unroll")                                                \
            for (int _ni = 0; _ni < 8; ++_ni) {                              \
                int _n = _ni * 16 + l15;                                     \
                bf16x8 _bf = *(const bf16x8*)&Bsm[_kt * TILE_ELEMS +         \
                             _n * 64 + (_g ^ (_n & 7)) * 8];                 \
                acc[0][_ni] = __builtin_amdgcn_mfma_f32_16x16x32_bf16(       \
                    AR[0][_kh], _bf, acc[0][_ni], 0, 0, 0);                  \
                acc[1][_ni] = __builtin_amdgcn_mfma_f32_16x16x32_bf16(       \
                    AR[1][_kh], _bf, acc[1][_ni], 0, 0, 0);                  \
            }                                                                \
        }                                                                    \
    }

__global__ __launch_bounds__(512, 1)
void gemm_kernel(const float* __restrict__ x,
                 const int* __restrict__ counts,
                 const int* __restrict__ rowlist,
                 const float* __restrict__ W,
                 const float* __restrict__ bias,
                 float* __restrict__ out) {
    const int bid  = blockIdx.x;
    const int e    = bid & 7;
    const int ns   = (bid >> 3) & 3;
    const int slot = bid >> 5;               // 0..7
    const int cnt  = counts[e];
    if (slot * BM >= cnt) return;            // uniform per-block, safe

    const int tid = threadIdx.x;
    const int w   = tid >> 6;                // 0..7
    const int ln  = tid & 63;
    const int q   = ln >> 4;
    const int l15 = ln & 15;
    const int wm  = w * 32;

    // ---- stage W-slice (e, ns): f32 -> bf16 -> swizzled LDS (prep-proven)
    const float* Wb = W + (size_t)e * (KDIM * NDIM) + ns * BN;
    #pragma unroll
    for (int it = 0; it < 16; ++it) {
        int gid = it * 512 + tid;            // granule 0..8191
        int kt  = gid >> 10;
        int rem = gid & 1023;
        int n   = rem & 127;                 // lanes: consecutive n -> coalesced
        int g   = rem >> 7;                  // 0..7
        int k0  = kt * 64 + g * 8;
        unsigned int p[4];
        #pragma unroll
        for (int jj = 0; jj < 4; ++jj) {
            unsigned int lo = f2bf_u(Wb[(size_t)(k0 + jj * 2) * NDIM + n]);
            unsigned int hi = f2bf_u(Wb[(size_t)(k0 + jj * 2 + 1) * NDIM + n]);
            p[jj] = lo | (hi << 16);
        }
        *(u32x4*)&Bsm[kt * TILE_ELEMS + n * 64 + (g ^ (n & 7)) * 8] =
            *(const u32x4*)p;
    }
    __syncthreads();                         // W-slice resident; only barrier

    const int ncol0 = ns * BN;

    for (int mc = slot; mc * BM < cnt; mc += SLOTS) {
        const int rb = mc * BM;
        int m_valid = cnt - rb;
        if (m_valid > BM) m_valid = BM;
        const int* rl = rowlist + e * NROWS + rb;

        const int r0i = wm + l15;
        const int r1i = wm + 16 + l15;
        const int ri0 = (r0i < m_valid) ? r0i : 0;
        const int ri1 = (r1i < m_valid) ? r1i : 0;
        const float* afrow0 = x + (size_t)rl[ri0] * KDIM;
        const float* afrow1 = x + (size_t)rl[ri1] * KDIM;

        f32x4 acc[2][8];
        #pragma unroll
        for (int mi = 0; mi < 2; ++mi)
            #pragma unroll
            for (int ni = 0; ni < 8; ++ni)
                acc[mi][ni] = (f32x4){0.f, 0.f, 0.f, 0.f};

        bf16x8 aQ[2][4], aR[2][4];
        LOAD_A_F32(0, aQ)
        LOAD_A_F32(1, aR)
        COMPUTE_Q(0, aQ)
        LOAD_A_F32(2, aQ)
        COMPUTE_Q(1, aR)
        LOAD_A_F32(3, aR)
        COMPUTE_Q(2, aQ)
        COMPUTE_Q(3, aR)

        // ---- epilogue: +bias, masked plain stores (C/D: col=l15, row=q*4+r)
        int grow[2][4];
        #pragma unroll
        for (int mi = 0; mi < 2; ++mi)
            #pragma unroll
            for (int r = 0; r < 4; ++r) {
                int mloc = wm + mi * 16 + q * 4 + r;
                grow[mi][r] = (mloc < m_valid) ? rl[mloc] : -1;
            }
        #pragma unroll
        for (int ni = 0; ni < 8; ++ni) {
            int col = ncol0 + ni * 16 + l15;
            float bv = bias[e * NDIM + col];
            #pragma unroll
            for (int mi = 0; mi < 2; ++mi)
                #pragma unroll
                for (int r = 0; r < 4; ++r)
                    if (grow[mi][r] >= 0)
                        out[(size_t)grow[mi][r] * NDIM + col] =
                            acc[mi][ni][r] + bv;
        }
    }
}

extern "C" void kernel_launch(void* const* d_in, const int* in_sizes, int n_in,
                              void* d_out, int out_size, void* d_ws, size_t ws_size,
                              hipStream_t stream) {
    const float* x      = (const float*)d_in[0];   // (16384, 512) f32
    const int*   groups = (const int*)d_in[1];     // (16384, 2) i32
    const float* W      = (const float*)d_in[2];   // (8, 512, 512) f32
    const float* b      = (const float*)d_in[3];   // (8, 512) f32
    float*       out    = (float*)d_out;           // (16384, 512) f32

    char* ws = (char*)d_ws;
    int*  counts  = (int*)ws;
    int*  rowlist = (int*)(ws + WS_ROWLIST_OFF);

    static bool attr_set = false;
    if (!attr_set) {
        hipFuncSetAttribute((const void*)gemm_kernel,
                            hipFuncAttributeMaxDynamicSharedMemorySize,
                            KT_PER * TILE_ELEMS * 2);      // 128KB dynamic LDS
        attr_set = true;
    }

    prep_kernel<<<NEXP, 256, 0, stream>>>(groups, counts, rowlist);
    // 8 e x 4 ns x 8 slots = 256 blocks = exactly 1/CU, XCD-pinned (bid&7).
    // Skew handled by the slot-strided m-loop inside the kernel.
    gemm_kernel<<<NEXP * NT_PER * SLOTS, 512, KT_PER * TILE_ELEMS * 2, stream>>>(
        x, counts, rowlist, W, b, out);
}

// Round 8
// 131.049 us; speedup vs baseline: 2.2571x; 2.2571x over previous
//
#include <hip/hip_runtime.h>
#include <hip/hip_bf16.h>

// SubnetGate = gathered grouped GEMM (B=16384, K=512, N=512, E=8, col 0).
// R10: spill-proof consolidation. R9 post-mortem: WRITE_SIZE 237MB (out=32MB)
// + VGPR pinned at 128 = ~200MB scratch spill from merging W-staging into
// gemm + raw-f32 A prefetch; dur tracks gemm 1:1 (fixed harness ~80us).
// R7's FETCH=10MB proved L3 serves x re-reads -> read x as f32 directly
// (xg/xconv deleted, ~15us prep saved), but keep register pressure bounded:
//  - gemm: R3's lean BM=64 geometry (acc = 32 VGPR) + R4's proven 4-deep
//    global_load_lds B pipeline. A raw-f32 2 steps ahead in 2 reg buffers
//    (16 VGPR each), PACKED AT END-OF-STEP so the compiler's auto waitcnt
//    is exactly vmcnt(12) (region-counted, no over-sync, no mid-loop drain).
//    Budget ~97 VGPR < 128 cap @ launch_bounds(256,2) -> 2 blk/CU, 8 waves.
//  - per-step explicit vmcnt (A=4,B=4 ops/step; prologue B0 A0 B1 A1 B2):
//    #newer(B[kt]) = {16,16,16,16,16,16,12,4} -> VM={12,16,16,16,16,16,12,4}.
//  - prep: scatter (8 blocks, proven) + Wtile build (1024 blocks, proven
//    swizzled layout). No xconv.
//
// ws layout:
//   [0,      32)       int counts[8]
//   [4096,   528384)   int rowlist[8][16384]
//   [528384, 4722688)  ushort Wtile[8][4 nt][8 kt][128n x 64k bf16, swizzled]

#define NROWS   16384
#define KDIM    512
#define NDIM    512
#define NEXP    8
#define BM      64
#define BN      128
#define NT_PER  4
#define KT_PER  8
#define MT_MAX  40                    // covers cnt up to 2560 (+12 sigma)
#define TILE_ELEMS (BN * 64)          // 8192 shorts = 16KB per kt-tile
#define WS_ROWLIST_OFF 4096
#define WS_WT_OFF      (4096 + NEXP * NROWS * 4)

typedef __bf16        bf16x8 __attribute__((ext_vector_type(8)));
typedef float         f32x4  __attribute__((ext_vector_type(4)));
typedef unsigned int  u32x4  __attribute__((ext_vector_type(4)));

__device__ __forceinline__ unsigned int f2bf_u(float f) {
    unsigned int u = __builtin_bit_cast(unsigned int, f);
    return (u + 0x7FFFu + ((u >> 16) & 1u)) >> 16;   // RNE f32->bf16
}

__device__ __forceinline__ void gl_lds16(const void* g, void* l) {
    __builtin_amdgcn_global_load_lds(
        (const __attribute__((address_space(1))) unsigned int*)g,
        (__attribute__((address_space(3))) unsigned int*)l, 16, 0, 0);
}

__device__ __forceinline__ bf16x8 pack_bf8(f32x4 lo, f32x4 hi) {
    u32x4 w;
    w.x = f2bf_u(lo.x) | (f2bf_u(lo.y) << 16);
    w.y = f2bf_u(lo.z) | (f2bf_u(lo.w) << 16);
    w.z = f2bf_u(hi.x) | (f2bf_u(hi.y) << 16);
    w.w = f2bf_u(hi.z) | (f2bf_u(hi.w) << 16);
    return __builtin_bit_cast(bf16x8, w);
}

// blocks [0,8): scatter -- block e scans all 16384 ids, 8 iters x (256 thr x
//   8 rows), ballot+prefix compaction, zero atomics; counts[e] plain store.
// blocks [8,1032): one quarter (32 n-cols) of a 16KB swizzled B-tile
//   (proven layout: granule (n,g) -> tile byte off n*128 + (g^(n&7))*16).
__global__ void prep_kernel(const float* __restrict__ W,
                            const int* __restrict__ groups,
                            int* __restrict__ counts,
                            int* __restrict__ rowlist,
                            unsigned short* __restrict__ Wtile) {
    const int bid = blockIdx.x;
    const int tid = threadIdx.x;

    if (bid < 8) {
        __shared__ int wcnt_s[4];
        __shared__ int woff_s[4];
        __shared__ int runb;
        const int e  = bid;
        const int w  = tid >> 6;
        const int ln = tid & 63;
        const unsigned long long below = (ln == 63) ? ~0ull >> 1
                                                    : (1ull << ln) - 1;
        int* dst = rowlist + e * NROWS;
        if (tid == 0) runb = 0;
        __syncthreads();
        for (int it = 0; it < NROWS / 2048; ++it) {      // 8 iterations
            int rbase = it * 2048 + tid * 8;
            u32x4 g0 = *(const u32x4*)&groups[rbase * 2];
            u32x4 g1 = *(const u32x4*)&groups[rbase * 2 + 4];
            u32x4 g2 = *(const u32x4*)&groups[rbase * 2 + 8];
            u32x4 g3 = *(const u32x4*)&groups[rbase * 2 + 12];
            bool h[8] = {(int)g0.x == e, (int)g0.z == e,
                         (int)g1.x == e, (int)g1.z == e,
                         (int)g2.x == e, (int)g2.z == e,
                         (int)g3.x == e, (int)g3.z == e};
            unsigned long long m[8];
            int c[8], tot = 0;
            #pragma unroll
            for (int jj = 0; jj < 8; ++jj) {
                m[jj] = __ballot(h[jj]);
                c[jj] = __popcll(m[jj]);
                tot += c[jj];
            }
            if (ln == 0) wcnt_s[w] = tot;
            __syncthreads();
            if (tid == 0) {
                int s = runb;
                #pragma unroll
                for (int i = 0; i < 4; ++i) { woff_s[i] = s; s += wcnt_s[i]; }
                runb = s;
            }
            __syncthreads();
            int base = woff_s[w];
            #pragma unroll
            for (int jj = 0; jj < 8; ++jj) {
                if (h[jj]) dst[base + __popcll(m[jj] & below)] = rbase + jj;
                base += c[jj];
            }
            __syncthreads();
        }
        if (tid == 0) counts[e] = runb;
    } else {
        // ---- W-tile build (proven layout), quarter-tile per block
        __shared__ __align__(16) unsigned short tl4[32 * 64];  // 4KB
        const int tb   = bid - 8;
        const int tile = tb >> 2;         // e*32 + nt*8 + kt
        const int qq   = tb & 3;
        const int e  = tile >> 5;
        const int nt = (tile >> 3) & 3;
        const int kt = tile & 7;
        const float* Wb = W + (size_t)e * (KDIM * NDIM);

        const int n   = qq * 32 + (tid & 31);
        const int g   = tid >> 5;               // 0..7
        const int col = nt * BN + n;
        unsigned int p[4];
        #pragma unroll
        for (int jj = 0; jj < 4; ++jj) {
            int k0 = kt * 64 + g * 8 + jj * 2;
            unsigned int lo = f2bf_u(Wb[(size_t)k0 * NDIM + col]);
            unsigned int hi = f2bf_u(Wb[(size_t)(k0 + 1) * NDIM + col]);
            p[jj] = lo | (hi << 16);
        }
        *(u32x4*)&tl4[(n & 31) * 64 + (g ^ (n & 7)) * 8] = *(const u32x4*)p;
        __syncthreads();
        unsigned short* dst = Wtile + (size_t)tile * TILE_ELEMS
                                    + ((size_t)qq * 256 + tid) * 8;
        *(u32x4*)dst = *(const u32x4*)&tl4[tid * 8];
    }
}

// ---------------- gemm ----------------
// Block = (e = bid&7 -> XCD pin; nt = (bid>>3)&3; mt = bid>>5). Grid 1280.
// 256 thr = 4 waves; wave w owns 16 rows [mt*64+w*16, +16) x 128 cols;
// acc[8] f32x4 = 32 VGPR.
// B: 4-deep LDS pipeline (64KB), global_load_lds staged 3-ahead (proven).
// A: lane (q,l15) owns ONE row rl[w*16+l15]; per step 4x f32x4 raw loads
//    (k = kt*64 + q*8, +32) issued 2 steps ahead into rA/rB (16 VGPR each);
//    packed to bf16 at END of the step before use (compiler's auto-wait at
//    the pack point is exactly vmcnt(12): #newer(A[kt+1]) = B[kt+2](4) +
//    A[kt+2](4) + B[kt+3](4); benign, keeps B lead intact).
// Per-step explicit VM = #newer(B[kt]) at entry (order B0 A0 B1 A1 B2, then
// step j: A[j+2](4), B[j+3](4)): {12(=pack bound),16,16,16,16,16,12,4}.

#define STAGE_B(KT, BUF)                                                     \
    {                                                                        \
        const unsigned short* _src = wt + (size_t)(KT) * TILE_ELEMS;         \
        _Pragma("unroll")                                                    \
        for (int _i = 0; _i < 4; ++_i) {                                     \
            int _off = (_i * 256 + tid) * 8;                                 \
            gl_lds16(_src + _off, &Bsm[BUF][_off]);                          \
        }                                                                    \
    }

#define LOAD_RAW(KT, R)                                                      \
    {                                                                        \
        const float* _p = afrow + (KT) * 64 + q * 8;                         \
        R[0] = *(const f32x4*)_p;                                            \
        R[1] = *(const f32x4*)(_p + 4);                                      \
        R[2] = *(const f32x4*)(_p + 32);                                     \
        R[3] = *(const f32x4*)(_p + 36);                                     \
    }

#define PACK(R, P)                                                           \
    {                                                                        \
        P[0] = pack_bf8(R[0], R[1]);                                         \
        P[1] = pack_bf8(R[2], R[3]);                                         \
    }

#define COMPUTE(BUF, P)                                                      \
    {                                                                        \
        _Pragma("unroll")                                                    \
        for (int _ni = 0; _ni < 8; ++_ni) {                                  \
            int _n = _ni * 16 + l15;                                         \
            bf16x8 _b0 = *(const bf16x8*)&Bsm[BUF][_n * 64 +                 \
                         (q ^ (_n & 7)) * 8];                                \
            acc[_ni] = __builtin_amdgcn_mfma_f32_16x16x32_bf16(              \
                P[0], _b0, acc[_ni], 0, 0, 0);                               \
        }                                                                    \
        _Pragma("unroll")                                                    \
        for (int _ni = 0; _ni < 8; ++_ni) {                                  \
            int _n = _ni * 16 + l15;                                         \
            bf16x8 _b1 = *(const bf16x8*)&Bsm[BUF][_n * 64 +                 \
                         ((4 + q) ^ (_n & 7)) * 8];                          \
            acc[_ni] = __builtin_amdgcn_mfma_f32_16x16x32_bf16(              \
                P[1], _b1, acc[_ni], 0, 0, 0);                               \
        }                                                                    \
    }

// PC: packed frags for this step; RN: raw buffer to load A[KT+2] into;
// RP: raw buffer holding A[KT+1]; PP: packed dest for A[KT+1].
#define KSTEP(KT, VM, PC, RN, RP, PP)                                        \
    {                                                                        \
        asm volatile("s_waitcnt vmcnt(" #VM ")" ::: "memory");               \
        __builtin_amdgcn_s_barrier();                                        \
        __builtin_amdgcn_sched_barrier(0);                                   \
        if ((KT) + 2 < KT_PER) LOAD_RAW((KT) + 2, RN)                        \
        if ((KT) + 3 < KT_PER) STAGE_B((KT) + 3, ((KT) + 3) & 3)             \
        __builtin_amdgcn_s_setprio(1);                                       \
        COMPUTE((KT) & 3, PC)                                                \
        __builtin_amdgcn_s_setprio(0);                                       \
        __builtin_amdgcn_sched_barrier(0);                                   \
        if ((KT) + 1 < KT_PER) PACK(RP, PP)                                  \
    }

__global__ __launch_bounds__(256, 2)
void gemm_kernel(const float* __restrict__ x,
                 const int* __restrict__ counts,
                 const int* __restrict__ rowlist,
                 const unsigned short* __restrict__ Wtile,
                 const float* __restrict__ bias,
                 float* __restrict__ out) {
    __shared__ __align__(16) unsigned short Bsm[4][TILE_ELEMS];  // 64KB

    const int bid = blockIdx.x;
    const int e   = bid & 7;
    const int nt  = (bid >> 3) & 3;
    const int mt  = bid >> 5;
    const int cnt = counts[e];
    const int rb  = mt * BM;
    if (rb >= cnt) return;
    int m_valid = cnt - rb;
    if (m_valid > BM) m_valid = BM;
    const int* rl = rowlist + e * NROWS + rb;

    const int tid = threadIdx.x;
    const int w   = tid >> 6;          // 0..3
    const int ln  = tid & 63;
    const int q   = ln >> 4;
    const int l15 = ln & 15;
    const int wm  = w * 16;

    const int am = wm + l15;
    const int ri = (am < m_valid) ? am : 0;
    const float* afrow = x + (size_t)rl[ri] * KDIM;

    const unsigned short* wt =
        Wtile + (size_t)((e * NT_PER + nt) * KT_PER) * TILE_ELEMS;

    f32x4 acc[8];
    #pragma unroll
    for (int ni = 0; ni < 8; ++ni) acc[ni] = (f32x4){0.f, 0.f, 0.f, 0.f};

    f32x4  rA[4], rB[4];
    bf16x8 pA[2], pB[2];

    // prologue (queue order B0 A0 B1 A1 B2 -> #newer(A0)=12, #newer(B0)=16)
    STAGE_B(0, 0)
    LOAD_RAW(0, rA)
    STAGE_B(1, 1)
    LOAD_RAW(1, rB)
    STAGE_B(2, 2)
    PACK(rA, pA)                       // compiler auto-wait = vmcnt(12)

    KSTEP(0, 12, pA, rA, rB, pB)       // compute A0; load A2->rA; pack A1->pB
    KSTEP(1, 16, pB, rB, rA, pA)       // compute A1; load A3->rB; pack A2->pA
    KSTEP(2, 16, pA, rA, rB, pB)
    KSTEP(3, 16, pB, rB, rA, pA)
    KSTEP(4, 16, pA, rA, rB, pB)
    KSTEP(5, 16, pB, rB, rA, pA)       // load A7->rB; pack A6->pA
    KSTEP(6, 12, pA, rA, rB, pB)       // no load; pack A7->pB
    KSTEP(7, 4,  pB, rB, rA, pA)       // tail

    // ---- epilogue: +bias, masked plain stores (C/D: col=l15, row=q*4+r)
    int grow[4];
    #pragma unroll
    for (int r = 0; r < 4; ++r) {
        int mloc = wm + q * 4 + r;
        grow[r] = (mloc < m_valid) ? rl[mloc] : -1;
    }
    const int ncol0 = nt * BN;
    #pragma unroll
    for (int ni = 0; ni < 8; ++ni) {
        int col = ncol0 + ni * 16 + l15;
        float bv = bias[e * NDIM + col];
        #pragma unroll
        for (int r = 0; r < 4; ++r)
            if (grow[r] >= 0)
                out[(size_t)grow[r] * NDIM + col] = acc[ni][r] + bv;
    }
}

extern "C" void kernel_launch(void* const* d_in, const int* in_sizes, int n_in,
                              void* d_out, int out_size, void* d_ws, size_t ws_size,
                              hipStream_t stream) {
    const float* x      = (const float*)d_in[0];   // (16384, 512) f32
    const int*   groups = (const int*)d_in[1];     // (16384, 2) i32
    const float* W      = (const float*)d_in[2];   // (8, 512, 512) f32
    const float* b      = (const float*)d_in[3];   // (8, 512) f32
    float*       out    = (float*)d_out;           // (16384, 512) f32

    char* ws = (char*)d_ws;
    int*            counts  = (int*)ws;
    int*            rowlist = (int*)(ws + WS_ROWLIST_OFF);
    unsigned short* Wtile   = (unsigned short*)(ws + WS_WT_OFF);

    // scatter(8) + Wtile(1024); no xconv
    prep_kernel<<<1032, 256, 0, stream>>>(W, groups, counts, rowlist, Wtile);
    // 8 e x 4 nt x 40 mt = 1280 blocks (skew-proof); inactive exit on
    // counts[e]. Active ~1024 @ 64KB LDS -> 2 blocks/CU, 8 waves/CU.
    gemm_kernel<<<NEXP * NT_PER * MT_MAX, 256, 0, stream>>>(
        x, counts, rowlist, Wtile, b, out);
}